// Round 8
// baseline (200.741 us; speedup 1.0000x reference)
//
#include <hip/hip_runtime.h>
#include <hip/hip_bf16.h>

// StandardAttention: B=2, N=4096, D=512, H=8, HD=64, causal.
// R8: attn is LDS-BW-bound (R7 arithmetic matches measured cycles). NS=2:
// each wave owns 2 q-stripes (32 rows) and reuses kf/vf register fragments
// across both -> K/V LDS reads per unit work halve. 256-thr blocks, 128-row
// supertiles, paired (st,31-st), 3-way key split (ws permitting) -> 768 blocks
// = 3 blocks/CU = 3 waves/SIMD. Static-shift softmax unchanged.

typedef __bf16 bf16_t;
typedef __bf16 bf16x4 __attribute__((ext_vector_type(4)));
typedef __bf16 bf16x8 __attribute__((ext_vector_type(8)));
typedef float  f32x4  __attribute__((ext_vector_type(4)));

// ---------------- conversion kernels ----------------

__global__ void convert_f32_bf16(const float* __restrict__ in, bf16_t* __restrict__ out) {
    int i = blockIdx.x * 256 + threadIdx.x;
    float4 v = ((const float4*)in)[i];
    bf16x4 o;
    o[0] = (bf16_t)v.x; o[1] = (bf16_t)v.y; o[2] = (bf16_t)v.z; o[3] = (bf16_t)v.w;
    ((bf16x4*)out)[i] = o;
}

// in: [512][N] fp32 -> out: [N][512] bf16, 64x64 tiles via LDS (coalesced both sides)
__global__ void transpose_tiled(const float* __restrict__ in, bf16_t* __restrict__ out, int N) {
    __shared__ bf16_t T[64][72];
    const int tid = threadIdx.x;
    const int n0 = blockIdx.x * 64, k0 = blockIdx.y * 64;
    #pragma unroll
    for (int pass = 0; pass < 4; ++pass) {
        int kk = pass * 16 + (tid >> 4), nn = (tid & 15) * 4;
        float4 v = *(const float4*)(in + (size_t)(k0 + kk) * N + n0 + nn);
        T[nn + 0][kk] = (bf16_t)v.x; T[nn + 1][kk] = (bf16_t)v.y;
        T[nn + 2][kk] = (bf16_t)v.z; T[nn + 3][kk] = (bf16_t)v.w;
    }
    __syncthreads();
    #pragma unroll
    for (int pass = 0; pass < 2; ++pass) {
        int n = pass * 32 + (tid >> 3), c8 = (tid & 7) * 8;
        *(bf16x8*)(out + (size_t)(n0 + n) * 512 + k0 + c8) = *(const bf16x8*)&T[n][c8];
    }
}

// ---------------- GEMM: C[M,*] = A[M,512] * Bt[*,512]^T + bias ----------------

template <int MODE, int TN>
__global__ __launch_bounds__(256) void gemm_bt(
    const bf16_t* __restrict__ A, const bf16_t* __restrict__ Bt,
    const float* __restrict__ bias,
    bf16_t* __restrict__ Qg, bf16_t* __restrict__ Kg, bf16_t* __restrict__ Vt,
    float* __restrict__ Cout)
{
    constexpr int NI = (TN == 128) ? 4 : 2;
    __shared__ bf16_t As[128][72];
    __shared__ bf16_t Bs[TN][72];
    const int tid  = threadIdx.x;
    const int wid  = tid >> 6, lane = tid & 63, l16 = lane & 15, quad = lane >> 4;
    const int wr   = (TN == 128) ? (wid >> 1) * 64 : wid * 32;
    const int wc   = (TN == 128) ? (wid & 1) * 64 : 0;
    const int m0   = blockIdx.y * 128, n0 = blockIdx.x * TN;

    f32x4 acc[NI][4] = {};

    for (int kk = 0; kk < 512; kk += 64) {
        __syncthreads();
        #pragma unroll
        for (int i = 0; i < 4; ++i) {
            int c = tid + i * 256, row = c >> 3, col8 = (c & 7) * 8;
            *(uint4*)&As[row][col8] = *(const uint4*)(A + (size_t)(m0 + row) * 512 + kk + col8);
        }
        #pragma unroll
        for (int i = 0; i < TN / 32; ++i) {
            int c = tid + i * 256, row = c >> 3, col8 = (c & 7) * 8;
            *(uint4*)&Bs[row][col8] = *(const uint4*)(Bt + (size_t)(n0 + row) * 512 + kk + col8);
        }
        __syncthreads();
        #pragma unroll
        for (int s = 0; s < 2; ++s) {
            bf16x8 a[NI], b[4];
            #pragma unroll
            for (int i = 0; i < NI; ++i) a[i] = *(const bf16x8*)&As[wr + i * 16 + l16][s * 32 + quad * 8];
            #pragma unroll
            for (int j = 0; j < 4; ++j) b[j] = *(const bf16x8*)&Bs[wc + j * 16 + l16][s * 32 + quad * 8];
            #pragma unroll
            for (int i = 0; i < NI; ++i)
                #pragma unroll
                for (int j = 0; j < 4; ++j)
                    acc[i][j] = __builtin_amdgcn_mfma_f32_16x16x32_bf16(a[i], b[j], acc[i][j], 0, 0, 0);
        }
    }

    const float qscale = 0.18033688011112042f;   // 0.125 * log2(e)
    #pragma unroll
    for (int i = 0; i < NI; ++i) {
        int mrow = m0 + wr + i * 16 + quad * 4;
        #pragma unroll
        for (int j = 0; j < 4; ++j) {
            int cgl = n0 + wc + j * 16 + l16;
            float bv = bias[cgl];
            #pragma unroll
            for (int r = 0; r < 4; ++r) {
                int m = mrow + r;
                float val = acc[i][j][r] + bv;
                if (MODE == 0) {
                    int which = cgl >> 9, hh = (cgl >> 6) & 7, hd = cgl & 63;
                    int b_ = m >> 12, n = m & 4095, bh = b_ * 8 + hh;
                    if (which == 0)      Qg[((size_t)bh * 4096 + n) * 64 + hd] = (bf16_t)(val * qscale);
                    else if (which == 1) Kg[((size_t)bh * 4096 + n) * 64 + hd] = (bf16_t)val;
                    else                 Vt[((size_t)bh * 64 + hd) * 4096 + n] = (bf16_t)val;
                } else {
                    Cout[(size_t)m * 512 + cgl] = val;
                }
            }
        }
    }
}

// ---------------- flash attention, NS=2 + split-K ----------------
// grid = 16 bh x 16 pairs x nsplit; 256 threads = 4 waves.
// Block runs supertiles st=pr and 31-pr (128 q-rows each); wave w owns stripes
// s=0,1 at rows st*128 + s*64 + w*16 (kf/vf register frags shared across both).
// Key range of supertile st (2st+2 tiles) divided [h*T/ns, (h+1)*T/ns).
// Static-shift softmax: partials additive, fp32 (o,l) out, combine at end.

__global__ __launch_bounds__(256, 3) void attn_ns2(
    const bf16_t* __restrict__ Qg, const bf16_t* __restrict__ Kg,
    const bf16_t* __restrict__ Vt,
    float* __restrict__ o_part, float* __restrict__ l_part, int nsplit)
{
    __shared__ bf16_t Ks[2][64][72];
    __shared__ bf16_t Vs[2][64][72];
    __shared__ bf16_t Ps[4][16][72];

    const int tid  = threadIdx.x;
    const int w    = tid >> 6, lane = tid & 63, l16 = lane & 15, quad = lane >> 4;
    const int bh   = blockIdx.x & 15, pr = (blockIdx.x >> 4) & 15, h = blockIdx.x >> 8;

    float* ob = o_part + (size_t)(h * 16 + bh) * 4096 * 64;
    float* lb = l_part + (size_t)(h * 16 + bh) * 4096;

    const int srow = tid >> 3, scol = (tid & 7) * 8;   // 2 chunks/thread per 64x64 tile
    const int srow1 = srow + 32;
    const float MSHIFT = 12.0f;

    bf16x8 ones;
    #pragma unroll
    for (int j = 0; j < 8; ++j) ones[j] = (bf16_t)1.0f;

    uint4 kr0, kr1, vr0, vr1;

    for (int ph = 0; ph < 2; ++ph) {
        const int st = ph ? (31 - pr) : pr;
        const int T  = 2 * st + 2;
        const int b0 = (h * T) / nsplit, b1 = ((h + 1) * T) / nsplit;

        // Q fragments for both stripes (pre-scaled by 0.125*log2e)
        int qrow[2];
        bf16x8 qf[2][2];
        #pragma unroll
        for (int s = 0; s < 2; ++s) {
            qrow[s] = st * 128 + s * 64 + w * 16 + l16;
            const bf16_t* qp = Qg + ((size_t)bh * 4096 + qrow[s]) * 64;
            qf[s][0] = *(const bf16x8*)(qp + quad * 8);
            qf[s][1] = *(const bf16x8*)(qp + 32 + quad * 8);
        }

        f32x4 o[2][4] = {};
        f32x4 lacc[2] = {};

        {   // preload first tile of this block's range
            const size_t kb = ((size_t)bh * 4096 + b0 * 64) * 64;
            const size_t vb = (size_t)bh * 64 * 4096 + b0 * 64;
            kr0 = *(const uint4*)(Kg + kb + (size_t)srow * 64 + scol);
            kr1 = *(const uint4*)(Kg + kb + (size_t)srow1 * 64 + scol);
            vr0 = *(const uint4*)(Vt + vb + (size_t)srow * 4096 + scol);
            vr1 = *(const uint4*)(Vt + vb + (size_t)srow1 * 4096 + scol);
        }
        __syncthreads();   // previous phase's buffer readers are done

        for (int kt = b0; kt < b1; ++kt) {
            const int cur = kt & 1;
            *(uint4*)&Ks[cur][srow][scol]  = kr0;
            *(uint4*)&Ks[cur][srow1][scol] = kr1;
            *(uint4*)&Vs[cur][srow][scol]  = vr0;
            *(uint4*)&Vs[cur][srow1][scol] = vr1;
            __syncthreads();

            if (kt + 1 < b1) {   // prefetch next tile; compute section covers it
                const size_t kb = ((size_t)bh * 4096 + (kt + 1) * 64) * 64;
                const size_t vb = (size_t)bh * 64 * 4096 + (kt + 1) * 64;
                kr0 = *(const uint4*)(Kg + kb + (size_t)srow * 64 + scol);
                kr1 = *(const uint4*)(Kg + kb + (size_t)srow1 * 64 + scol);
                vr0 = *(const uint4*)(Vt + vb + (size_t)srow * 4096 + scol);
                vr1 = *(const uint4*)(Vt + vb + (size_t)srow1 * 4096 + scol);
            }

            // fragments, loaded ONCE and reused by both stripes
            bf16x8 kf[4][2], vf[4][2];
            #pragma unroll
            for (int cb = 0; cb < 4; ++cb) {
                kf[cb][0] = *(const bf16x8*)&Ks[cur][cb * 16 + l16][quad * 8];
                kf[cb][1] = *(const bf16x8*)&Ks[cur][cb * 16 + l16][32 + quad * 8];
            }
            #pragma unroll
            for (int j = 0; j < 4; ++j) {
                vf[j][0] = *(const bf16x8*)&Vs[cur][j * 16 + l16][quad * 8];
                vf[j][1] = *(const bf16x8*)&Vs[cur][j * 16 + l16][32 + quad * 8];
            }

            #pragma unroll
            for (int s = 0; s < 2; ++s) {
                const int diag = 2 * st + s;
                if (kt > diag) continue;   // block-uniform: trims s=0 at kt=2st+1

                // S^T = K * Q^T : lane holds col q, rows key = cb*16 + quad*4 + r
                f32x4 sv[4] = {};
                #pragma unroll
                for (int cb = 0; cb < 4; ++cb) {
                    sv[cb] = __builtin_amdgcn_mfma_f32_16x16x32_bf16(kf[cb][0], qf[s][0], sv[cb], 0, 0, 0);
                    sv[cb] = __builtin_amdgcn_mfma_f32_16x16x32_bf16(kf[cb][1], qf[s][1], sv[cb], 0, 0, 0);
                }

                if (kt == diag) {   // causal mask on this stripe's diagonal tile
                    #pragma unroll
                    for (int cb = 0; cb < 4; ++cb) {
                        const int keyg = kt * 64 + cb * 16 + quad * 4;
                        #pragma unroll
                        for (int r = 0; r < 4; ++r)
                            if (keyg + r > qrow[s]) sv[cb][r] = -1e30f;
                    }
                }

                // P = exp2(s - MSHIFT), pack bf16, ds_write_b64 into A-layout region
                #pragma unroll
                for (int cb = 0; cb < 4; ++cb) {
                    bf16x4 pk;
                    #pragma unroll
                    for (int r = 0; r < 4; ++r)
                        pk[r] = (bf16_t)__builtin_amdgcn_exp2f(sv[cb][r] - MSHIFT);
                    *(bf16x4*)&Ps[w][l16][cb * 16 + quad * 4] = pk;
                }
                bf16x8 pa0 = *(const bf16x8*)&Ps[w][l16][quad * 8];
                bf16x8 pa1 = *(const bf16x8*)&Ps[w][l16][32 + quad * 8];

                #pragma unroll
                for (int j = 0; j < 4; ++j) {
                    o[s][j] = __builtin_amdgcn_mfma_f32_16x16x32_bf16(pa0, vf[j][0], o[s][j], 0, 0, 0);
                    o[s][j] = __builtin_amdgcn_mfma_f32_16x16x32_bf16(pa1, vf[j][1], o[s][j], 0, 0, 0);
                }
                lacc[s] = __builtin_amdgcn_mfma_f32_16x16x32_bf16(pa0, ones, lacc[s], 0, 0, 0);
                lacc[s] = __builtin_amdgcn_mfma_f32_16x16x32_bf16(pa1, ones, lacc[s], 0, 0, 0);
            }
        }

        // write fp32 partials (unnormalized)
        #pragma unroll
        for (int s = 0; s < 2; ++s)
            #pragma unroll
            for (int r = 0; r < 4; ++r) {
                int n = st * 128 + s * 64 + w * 16 + quad * 4 + r;
                #pragma unroll
                for (int j = 0; j < 4; ++j)
                    ob[(size_t)n * 64 + j * 16 + l16] = o[s][j][r];
                if (l16 == 0) lb[n] = lacc[s][r];
            }
    }
}

// combine: Og[b][n][hh*64+hd] = sum_h(o_h) / sum_h(l_h), bf16
__global__ void combine_kernel(const float* __restrict__ o_part,
                               const float* __restrict__ l_part,
                               bf16_t* __restrict__ Og, int ns)
{
    int t = blockIdx.x * 256 + threadIdx.x;      // 524288 threads
    int oct = t & 7, n = (t >> 3) & 4095, bh = t >> 15;
    size_t base = ((size_t)bh * 4096 + n) * 64 + oct * 8;
    f32x4 s0 = {}, s1 = {};
    float l = 0.f;
    for (int h = 0; h < ns; ++h) {
        const float* op = o_part + (size_t)h * 16 * 4096 * 64 + base;
        s0 += *(const f32x4*)op;
        s1 += *(const f32x4*)(op + 4);
        l  += l_part[(size_t)h * 16 * 4096 + (size_t)bh * 4096 + n];
    }
    float inv = 1.0f / l;
    bf16x8 res;
    #pragma unroll
    for (int j = 0; j < 4; ++j) {
        res[j]     = (bf16_t)(s0[j] * inv);
        res[j + 4] = (bf16_t)(s1[j] * inv);
    }
    *(bf16x8*)(Og + ((size_t)((bh >> 3) * 4096 + n)) * 512 + (bh & 7) * 64 + oct * 8) = res;
}

// ---------------- launch ----------------

extern "C" void kernel_launch(void* const* d_in, const int* in_sizes, int n_in,
                              void* d_out, int out_size, void* d_ws, size_t ws_size,
                              hipStream_t stream) {
    const float* x    = (const float*)d_in[0];   // [2,4096,512]
    const float* Wqkv = (const float*)d_in[1];   // [512,1536]
    const float* bqkv = (const float*)d_in[2];   // [1536]
    const float* Wout = (const float*)d_in[3];   // [512,512]
    const float* bout = (const float*)d_in[4];   // [512]
    float* out = (float*)d_out;                  // [2,4096,512] fp32

    char* ws = (char*)d_ws;
    bf16_t* xb  = (bf16_t*)(ws);                 // 8 MB (reused as Og)
    bf16_t* WqT = (bf16_t*)(ws + 8388608);       // 1.5 MB
    bf16_t* WoT = (bf16_t*)(ws + 9961472);       // 0.5 MB
    bf16_t* Qg  = (bf16_t*)(ws + 10485760);      // 8 MB (pre-scaled)
    bf16_t* Kg  = (bf16_t*)(ws + 18874368);      // 8 MB
    bf16_t* Vt  = (bf16_t*)(ws + 27262976);      // 8 MB ([bh][64][4096])

    // partials: nsplit slabs of o (16 MB each) then nsplit slabs of l (256 KB)
    const int nsplit = (ws_size >= 86769664ULL) ? 3 : 2;
    float* o_part = (float*)(ws + 35651584);
    float* l_part = (float*)(ws + 35651584 + (size_t)nsplit * 16777216);

    convert_f32_bf16<<<4096, 256, 0, stream>>>(x, xb);
    transpose_tiled<<<dim3(24, 8), 256, 0, stream>>>(Wqkv, WqT, 1536);
    transpose_tiled<<<dim3(8, 8), 256, 0, stream>>>(Wout, WoT, 512);

    gemm_bt<0, 128><<<dim3(12, 64), 256, 0, stream>>>(xb, WqT, bqkv, Qg, Kg, Vt, nullptr);

    attn_ns2<<<256 * nsplit, 256, 0, stream>>>(Qg, Kg, Vt, o_part, l_part, nsplit);
    combine_kernel<<<2048, 256, 0, stream>>>(o_part, l_part, xb /* Og */, nsplit);

    gemm_bt<1, 64><<<dim3(8, 64), 256, 0, stream>>>(xb, WoT, bout, nullptr, nullptr, nullptr, out);
}

// Round 9
// 191.023 us; speedup vs baseline: 1.0509x; 1.0509x over previous
//
#include <hip/hip_runtime.h>
#include <hip/hip_bf16.h>

// StandardAttention: B=2, N=4096, D=512, H=8, HD=64, causal.
// R9: non-attn budget. GEMMs rebuilt m97-style: global_load_lds width=16
// direct-to-LDS staging, unpadded LDS + XOR chunk swizzle (permutation applied
// on the global-address side; reads are 2-way-conflict-free). QKV epilogue now
// writes V coalesced [bh][n][64]; dedicated swizzled transpose_v builds
// Vt [bh][64][4096]. attn unchanged from R8 (isolate the GEMM delta).

typedef __bf16 bf16_t;
typedef __bf16 bf16x4 __attribute__((ext_vector_type(4)));
typedef __bf16 bf16x8 __attribute__((ext_vector_type(8)));
typedef float  f32x4  __attribute__((ext_vector_type(4)));

// async global->LDS, 16 B per lane; lds dst must be wave-uniform base (HW puts
// lane i at base + i*16)
__device__ __forceinline__ void gload_lds16(const bf16_t* g, bf16_t* l) {
    __builtin_amdgcn_global_load_lds(
        (const __attribute__((address_space(1))) void*)g,
        (__attribute__((address_space(3))) void*)l, 16, 0, 0);
}

// ---------------- conversion kernels ----------------

__global__ void convert_f32_bf16(const float* __restrict__ in, bf16_t* __restrict__ out) {
    int i = blockIdx.x * 256 + threadIdx.x;
    float4 v = ((const float4*)in)[i];
    bf16x4 o;
    o[0] = (bf16_t)v.x; o[1] = (bf16_t)v.y; o[2] = (bf16_t)v.z; o[3] = (bf16_t)v.w;
    ((bf16x4*)out)[i] = o;
}

// in: [512][N] fp32 -> out: [N][512] bf16, 64x64 tiles via LDS
__global__ void transpose_tiled(const float* __restrict__ in, bf16_t* __restrict__ out, int N) {
    __shared__ bf16_t T[64][72];
    const int tid = threadIdx.x;
    const int n0 = blockIdx.x * 64, k0 = blockIdx.y * 64;
    #pragma unroll
    for (int pass = 0; pass < 4; ++pass) {
        int kk = pass * 16 + (tid >> 4), nn = (tid & 15) * 4;
        float4 v = *(const float4*)(in + (size_t)(k0 + kk) * N + n0 + nn);
        T[nn + 0][kk] = (bf16_t)v.x; T[nn + 1][kk] = (bf16_t)v.y;
        T[nn + 2][kk] = (bf16_t)v.z; T[nn + 3][kk] = (bf16_t)v.w;
    }
    __syncthreads();
    #pragma unroll
    for (int pass = 0; pass < 2; ++pass) {
        int n = pass * 32 + (tid >> 3), c8 = (tid & 7) * 8;
        *(bf16x8*)(out + (size_t)(n0 + n) * 512 + k0 + c8) = *(const bf16x8*)&T[n][c8];
    }
}

// Vg [bh][4096][64] -> Vt [bh][64][4096]; 64x64 tiles, XOR-swizzled LDS
__global__ void transpose_v(const bf16_t* __restrict__ Vg, bf16_t* __restrict__ Vt) {
    __shared__ bf16_t T[64 * 64];      // cell (hd, cn8) at chunk hd*8 + (cn ^ (hd>>3))
    const int tid = threadIdx.x;
    const int bh = blockIdx.x >> 6, n0 = (blockIdx.x & 63) * 64;
    const bf16_t* src = Vg + ((size_t)bh * 4096 + n0) * 64;
    #pragma unroll
    for (int i = 0; i < 2; ++i) {
        int c = tid + i * 256, n = c >> 3, h8 = (c & 7) * 8;
        bf16x8 v = *(const bf16x8*)(src + (size_t)n * 64 + h8);
        const int swz = (n >> 3) ^ (h8 >> 3);
        bf16_t* base = &T[swz * 8 + (n & 7)];
        #pragma unroll
        for (int j = 0; j < 8; ++j) base[(h8 + j) * 64] = v[j];
    }
    __syncthreads();
    bf16_t* dst = Vt + (size_t)bh * 64 * 4096 + n0;
    #pragma unroll
    for (int i = 0; i < 2; ++i) {
        int c = tid + i * 256, hd = c >> 3, cn = c & 7;
        *(bf16x8*)(dst + (size_t)hd * 4096 + cn * 8) =
            *(const bf16x8*)&T[hd * 64 + ((cn ^ (hd >> 3)) * 8)];
    }
}

// ---------------- GEMM: C[M,*] = A[M,512] * Bt[*,512]^T + bias ----------------
// m97-style: global_load_lds(16B) staging, unpadded LDS, XOR chunk swizzle
// (chunk c of row r stored at slot c ^ (r&7); applied on the global side).
// MODE 0: QKV -> Q (pre-scaled 0.125*log2e), K, V all [BH][4096][64] bf16
// MODE 1: out projection -> Cout fp32 [M,512]

template <int MODE, int TN>
__global__ __launch_bounds__(256) void gemm_bt(
    const bf16_t* __restrict__ A, const bf16_t* __restrict__ Bt,
    const float* __restrict__ bias,
    bf16_t* __restrict__ Qg, bf16_t* __restrict__ Kg, bf16_t* __restrict__ Vg,
    float* __restrict__ Cout)
{
    constexpr int NI = (TN == 128) ? 4 : 2;
    __shared__ bf16_t As[128 * 64];
    __shared__ bf16_t Bs[TN * 64];
    const int tid  = threadIdx.x;
    const int wid  = tid >> 6, lane = tid & 63, l16 = lane & 15, quad = lane >> 4;
    const int l8   = l16 & 7;
    const int wr   = (TN == 128) ? (wid >> 1) * 64 : wid * 32;
    const int wc   = (TN == 128) ? (wid & 1) * 64 : 0;
    const int m0   = blockIdx.y * 128, n0 = blockIdx.x * TN;

    f32x4 acc[NI][4] = {};

    for (int kk = 0; kk < 512; kk += 64) {
        __syncthreads();                       // readers done with LDS
        #pragma unroll
        for (int i = 0; i < 4; ++i) {          // A: 1024 slots (128 rows x 8 chunks)
            int slot = tid + i * 256;
            int row = slot >> 3, cg = (slot & 7) ^ (row & 7);
            gload_lds16(A + (size_t)(m0 + row) * 512 + kk + cg * 8,
                        (bf16_t*)((char*)As + ((i * 256 + (wid << 6)) << 4)));
        }
        #pragma unroll
        for (int i = 0; i < TN / 32; ++i) {    // B: TN*8 slots
            int slot = tid + i * 256;
            int row = slot >> 3, cg = (slot & 7) ^ (row & 7);
            gload_lds16(Bt + (size_t)(n0 + row) * 512 + kk + cg * 8,
                        (bf16_t*)((char*)Bs + ((i * 256 + (wid << 6)) << 4)));
        }
        __syncthreads();                       // vmcnt(0) drain -> staged
        #pragma unroll
        for (int s = 0; s < 2; ++s) {
            const int sw = (s * 4 + quad);
            bf16x8 a[NI], b[4];
            #pragma unroll
            for (int i = 0; i < NI; ++i) {
                int row = wr + i * 16 + l16;
                a[i] = *(const bf16x8*)&As[(row * 8 + (sw ^ l8)) * 8];
            }
            #pragma unroll
            for (int j = 0; j < 4; ++j) {
                int row = wc + j * 16 + l16;
                b[j] = *(const bf16x8*)&Bs[(row * 8 + (sw ^ l8)) * 8];
            }
            #pragma unroll
            for (int i = 0; i < NI; ++i)
                #pragma unroll
                for (int j = 0; j < 4; ++j)
                    acc[i][j] = __builtin_amdgcn_mfma_f32_16x16x32_bf16(a[i], b[j], acc[i][j], 0, 0, 0);
        }
    }

    const float qscale = 0.18033688011112042f;   // 0.125 * log2(e)
    #pragma unroll
    for (int i = 0; i < NI; ++i) {
        int mrow = m0 + wr + i * 16 + quad * 4;
        #pragma unroll
        for (int j = 0; j < 4; ++j) {
            int cgl = n0 + wc + j * 16 + l16;
            float bv = bias[cgl];
            #pragma unroll
            for (int r = 0; r < 4; ++r) {
                int m = mrow + r;
                float val = acc[i][j][r] + bv;
                if (MODE == 0) {
                    int which = cgl >> 9, hh = (cgl >> 6) & 7, hd = cgl & 63;
                    int b_ = m >> 12, n = m & 4095, bh = b_ * 8 + hh;
                    size_t idx = ((size_t)bh * 4096 + n) * 64 + hd;
                    if (which == 0)      Qg[idx] = (bf16_t)(val * qscale);
                    else if (which == 1) Kg[idx] = (bf16_t)val;
                    else                 Vg[idx] = (bf16_t)val;     // coalesced now
                } else {
                    Cout[(size_t)m * 512 + cgl] = val;
                }
            }
        }
    }
}

// ---------------- flash attention, NS=2 + split-K (unchanged from R8) ----------------

__global__ __launch_bounds__(256, 3) void attn_ns2(
    const bf16_t* __restrict__ Qg, const bf16_t* __restrict__ Kg,
    const bf16_t* __restrict__ Vt,
    float* __restrict__ o_part, float* __restrict__ l_part, int nsplit)
{
    __shared__ bf16_t Ks[2][64][72];
    __shared__ bf16_t Vs[2][64][72];
    __shared__ bf16_t Ps[4][16][72];

    const int tid  = threadIdx.x;
    const int w    = tid >> 6, lane = tid & 63, l16 = lane & 15, quad = lane >> 4;
    const int bh   = blockIdx.x & 15, pr = (blockIdx.x >> 4) & 15, h = blockIdx.x >> 8;

    float* ob = o_part + (size_t)(h * 16 + bh) * 4096 * 64;
    float* lb = l_part + (size_t)(h * 16 + bh) * 4096;

    const int srow = tid >> 3, scol = (tid & 7) * 8;
    const int srow1 = srow + 32;
    const float MSHIFT = 12.0f;

    bf16x8 ones;
    #pragma unroll
    for (int j = 0; j < 8; ++j) ones[j] = (bf16_t)1.0f;

    uint4 kr0, kr1, vr0, vr1;

    for (int ph = 0; ph < 2; ++ph) {
        const int st = ph ? (31 - pr) : pr;
        const int T  = 2 * st + 2;
        const int b0 = (h * T) / nsplit, b1 = ((h + 1) * T) / nsplit;

        int qrow[2];
        bf16x8 qf[2][2];
        #pragma unroll
        for (int s = 0; s < 2; ++s) {
            qrow[s] = st * 128 + s * 64 + w * 16 + l16;
            const bf16_t* qp = Qg + ((size_t)bh * 4096 + qrow[s]) * 64;
            qf[s][0] = *(const bf16x8*)(qp + quad * 8);
            qf[s][1] = *(const bf16x8*)(qp + 32 + quad * 8);
        }

        f32x4 o[2][4] = {};
        f32x4 lacc[2] = {};

        {
            const size_t kb = ((size_t)bh * 4096 + b0 * 64) * 64;
            const size_t vb = (size_t)bh * 64 * 4096 + b0 * 64;
            kr0 = *(const uint4*)(Kg + kb + (size_t)srow * 64 + scol);
            kr1 = *(const uint4*)(Kg + kb + (size_t)srow1 * 64 + scol);
            vr0 = *(const uint4*)(Vt + vb + (size_t)srow * 4096 + scol);
            vr1 = *(const uint4*)(Vt + vb + (size_t)srow1 * 4096 + scol);
        }
        __syncthreads();

        for (int kt = b0; kt < b1; ++kt) {
            const int cur = kt & 1;
            *(uint4*)&Ks[cur][srow][scol]  = kr0;
            *(uint4*)&Ks[cur][srow1][scol] = kr1;
            *(uint4*)&Vs[cur][srow][scol]  = vr0;
            *(uint4*)&Vs[cur][srow1][scol] = vr1;
            __syncthreads();

            if (kt + 1 < b1) {
                const size_t kb = ((size_t)bh * 4096 + (kt + 1) * 64) * 64;
                const size_t vb = (size_t)bh * 64 * 4096 + (kt + 1) * 64;
                kr0 = *(const uint4*)(Kg + kb + (size_t)srow * 64 + scol);
                kr1 = *(const uint4*)(Kg + kb + (size_t)srow1 * 64 + scol);
                vr0 = *(const uint4*)(Vt + vb + (size_t)srow * 4096 + scol);
                vr1 = *(const uint4*)(Vt + vb + (size_t)srow1 * 4096 + scol);
            }

            bf16x8 kf[4][2], vf[4][2];
            #pragma unroll
            for (int cb = 0; cb < 4; ++cb) {
                kf[cb][0] = *(const bf16x8*)&Ks[cur][cb * 16 + l16][quad * 8];
                kf[cb][1] = *(const bf16x8*)&Ks[cur][cb * 16 + l16][32 + quad * 8];
            }
            #pragma unroll
            for (int j = 0; j < 4; ++j) {
                vf[j][0] = *(const bf16x8*)&Vs[cur][j * 16 + l16][quad * 8];
                vf[j][1] = *(const bf16x8*)&Vs[cur][j * 16 + l16][32 + quad * 8];
            }

            #pragma unroll
            for (int s = 0; s < 2; ++s) {
                const int diag = 2 * st + s;
                if (kt > diag) continue;

                f32x4 sv[4] = {};
                #pragma unroll
                for (int cb = 0; cb < 4; ++cb) {
                    sv[cb] = __builtin_amdgcn_mfma_f32_16x16x32_bf16(kf[cb][0], qf[s][0], sv[cb], 0, 0, 0);
                    sv[cb] = __builtin_amdgcn_mfma_f32_16x16x32_bf16(kf[cb][1], qf[s][1], sv[cb], 0, 0, 0);
                }

                if (kt == diag) {
                    #pragma unroll
                    for (int cb = 0; cb < 4; ++cb) {
                        const int keyg = kt * 64 + cb * 16 + quad * 4;
                        #pragma unroll
                        for (int r = 0; r < 4; ++r)
                            if (keyg + r > qrow[s]) sv[cb][r] = -1e30f;
                    }
                }

                #pragma unroll
                for (int cb = 0; cb < 4; ++cb) {
                    bf16x4 pk;
                    #pragma unroll
                    for (int r = 0; r < 4; ++r)
                        pk[r] = (bf16_t)__builtin_amdgcn_exp2f(sv[cb][r] - MSHIFT);
                    *(bf16x4*)&Ps[w][l16][cb * 16 + quad * 4] = pk;
                }
                bf16x8 pa0 = *(const bf16x8*)&Ps[w][l16][quad * 8];
                bf16x8 pa1 = *(const bf16x8*)&Ps[w][l16][32 + quad * 8];

                #pragma unroll
                for (int j = 0; j < 4; ++j) {
                    o[s][j] = __builtin_amdgcn_mfma_f32_16x16x32_bf16(pa0, vf[j][0], o[s][j], 0, 0, 0);
                    o[s][j] = __builtin_amdgcn_mfma_f32_16x16x32_bf16(pa1, vf[j][1], o[s][j], 0, 0, 0);
                }
                lacc[s] = __builtin_amdgcn_mfma_f32_16x16x32_bf16(pa0, ones, lacc[s], 0, 0, 0);
                lacc[s] = __builtin_amdgcn_mfma_f32_16x16x32_bf16(pa1, ones, lacc[s], 0, 0, 0);
            }
        }

        #pragma unroll
        for (int s = 0; s < 2; ++s)
            #pragma unroll
            for (int r = 0; r < 4; ++r) {
                int n = st * 128 + s * 64 + w * 16 + quad * 4 + r;
                #pragma unroll
                for (int j = 0; j < 4; ++j)
                    ob[(size_t)n * 64 + j * 16 + l16] = o[s][j][r];
                if (l16 == 0) lb[n] = lacc[s][r];
            }
    }
}

// combine: Og[b][n][hh*64+hd] = sum_h(o_h) / sum_h(l_h), bf16
__global__ void combine_kernel(const float* __restrict__ o_part,
                               const float* __restrict__ l_part,
                               bf16_t* __restrict__ Og, int ns)
{
    int t = blockIdx.x * 256 + threadIdx.x;
    int oct = t & 7, n = (t >> 3) & 4095, bh = t >> 15;
    size_t base = ((size_t)bh * 4096 + n) * 64 + oct * 8;
    f32x4 s0 = {}, s1 = {};
    float l = 0.f;
    for (int h = 0; h < ns; ++h) {
        const float* op = o_part + (size_t)h * 16 * 4096 * 64 + base;
        s0 += *(const f32x4*)op;
        s1 += *(const f32x4*)(op + 4);
        l  += l_part[(size_t)h * 16 * 4096 + (size_t)bh * 4096 + n];
    }
    float inv = 1.0f / l;
    bf16x8 res;
    #pragma unroll
    for (int j = 0; j < 4; ++j) {
        res[j]     = (bf16_t)(s0[j] * inv);
        res[j + 4] = (bf16_t)(s1[j] * inv);
    }
    *(bf16x8*)(Og + ((size_t)((bh >> 3) * 4096 + n)) * 512 + (bh & 7) * 64 + oct * 8) = res;
}

// ---------------- launch ----------------

extern "C" void kernel_launch(void* const* d_in, const int* in_sizes, int n_in,
                              void* d_out, int out_size, void* d_ws, size_t ws_size,
                              hipStream_t stream) {
    const float* x    = (const float*)d_in[0];   // [2,4096,512]
    const float* Wqkv = (const float*)d_in[1];   // [512,1536]
    const float* bqkv = (const float*)d_in[2];   // [1536]
    const float* Wout = (const float*)d_in[3];   // [512,512]
    const float* bout = (const float*)d_in[4];   // [512]
    float* out = (float*)d_out;                  // [2,4096,512] fp32

    char* ws = (char*)d_ws;
    bf16_t* xb  = (bf16_t*)(ws);                 // 8 MB (reused as Og)
    bf16_t* WqT = (bf16_t*)(ws + 8388608);       // 1.5 MB
    bf16_t* WoT = (bf16_t*)(ws + 9961472);       // 0.5 MB
    bf16_t* Qg  = (bf16_t*)(ws + 10485760);      // 8 MB (pre-scaled)
    bf16_t* Kg  = (bf16_t*)(ws + 18874368);      // 8 MB
    bf16_t* Vt  = (bf16_t*)(ws + 27262976);      // 8 MB ([bh][64][4096])
    // Vg is dead after transpose_v; it overlaps o_part slab 0 (written later by attn)
    bf16_t* Vg  = (bf16_t*)(ws + 35651584);      // 8 MB ([bh][n][64])

    const int nsplit = (ws_size >= 86769664ULL) ? 3 : 2;
    float* o_part = (float*)(ws + 35651584);
    float* l_part = (float*)(ws + 35651584 + (size_t)nsplit * 16777216);

    convert_f32_bf16<<<4096, 256, 0, stream>>>(x, xb);
    transpose_tiled<<<dim3(24, 8), 256, 0, stream>>>(Wqkv, WqT, 1536);
    transpose_tiled<<<dim3(8, 8), 256, 0, stream>>>(Wout, WoT, 512);

    gemm_bt<0, 128><<<dim3(12, 64), 256, 0, stream>>>(xb, WqT, bqkv, Qg, Kg, Vg, nullptr);
    transpose_v<<<1024, 256, 0, stream>>>(Vg, Vt);

    attn_ns2<<<256 * nsplit, 256, 0, stream>>>(Qg, Kg, Vt, o_part, l_part, nsplit);
    combine_kernel<<<2048, 256, 0, stream>>>(o_part, l_part, xb /* Og */, nsplit);

    gemm_bt<1, 64><<<dim3(8, 64), 256, 0, stream>>>(xb, WoT, bout, nullptr, nullptr, nullptr, out);
}